// Round 2
// 1045.331 us; speedup vs baseline: 1.0348x; 1.0348x over previous
//
#include <hip/hip_runtime.h>
#include <math.h>

// Problem constants
#define NNODE 256
#define FF    255      // feature dim
#define F2    510      // 2*F
#define EE    65536
#define HH    2048
#define OUTN  32640

typedef float vf4 __attribute__((ext_vector_type(4)));

// Workspace layout (float offsets)
#define OFF_W1P 0                    // 3 * 512*512   (W1 padded, b1 in col 510, unit row 510)
#define OFF_W2P 786432               // 3 * 256*512   (W2 padded, b2 in col 510, unit row 255)
#define OFF_W3P 1179648              // 3 * 256*256   (W3 padded, b3 in col 255)
#define OFF_T   1376256              // 3 * 256*512   T = W2p @ W1p
#define OFF_K   1769472              // 3 * 256*512   K = W3p @ T   (col 510 = beff)
#define OFF_KDT 2162688              // 3 * 256*256   (Ka-Kb)^T, [k][o]
#define OFF_KBT 2359296              // 3 * 256*256   Kb^T, [k][o]
#define OFF_BEFF 2555904             // 3 * 256
#define OFF_GP  2556672              // 4 * 256*256   g0..g3 (padded col 255 = 0)
#define OFF_U   2818816              // 256*256
#define OFF_V   2884352              // 256*256  (must be right after U)
#define OFF_G3C 2949888              // 65280 compact g3.ravel()
#define OFF_Y   3015168              // 2048
#define OFF_MASK_BYTES (3017216L*4)  // 256*4 u64 = 8192 bytes

struct PrepArgs {
    const float* x;
    const int*   ei;
    const float* W1[3]; const float* b1[3];
    const float* W2[3]; const float* b2[3];
    const float* W3[3]; const float* b3[3];
};

// Pads weights with affine augmentation, pads x, builds adjacency bitmask.
__global__ __launch_bounds__(256) void prep_kernel(PrepArgs a, float* __restrict__ ws,
                                                   unsigned long long* __restrict__ mask) {
    int b = blockIdx.x, t = threadIdx.x;
    if (b < 1536) {                      // W1p: [512][512] per layer
        int l = b >> 9, r = b & 511;
        const float* W1 = a.W1[l]; const float* b1 = a.b1[l];
        float* dst = ws + OFF_W1P + l * (512 * 512) + r * 512;
        for (int c = t; c < 512; c += 256) {
            float v = 0.f;
            if (r < F2 && c < F2)      v = W1[r * F2 + c];
            else if (c == F2)          v = (r < F2) ? b1[r] : ((r == F2) ? 1.f : 0.f);
            dst[c] = v;
        }
    } else if (b < 2304) {               // W2p: [256][512] per layer
        int bb = b - 1536; int l = bb >> 8, r = bb & 255;
        const float* W2 = a.W2[l]; const float* b2 = a.b2[l];
        float* dst = ws + OFF_W2P + l * (256 * 512) + r * 512;
        for (int c = t; c < 512; c += 256) {
            float v = 0.f;
            if (r < FF && c < F2)      v = W2[r * F2 + c];
            else if (c == F2)          v = (r < FF) ? b2[r] : 1.f;   // row 255 = unit
            dst[c] = v;
        }
    } else if (b < 3072) {               // W3p: [256][256] per layer
        int bb = b - 2304; int l = bb >> 8, r = bb & 255;
        float* dst = ws + OFF_W3P + l * (256 * 256) + r * 256;
        float v = 0.f;
        if (r < FF) {
            if (t < FF)       v = a.W3[l][r * FF + t];
            else if (t == FF) v = a.b3[l][r];
        }
        dst[t] = v;
    } else if (b < 3328) {               // gp0: padded x
        int r = b - 3072;
        float* dst = ws + OFF_GP + r * 256;
        dst[t] = (t < FF) ? a.x[r * FF + t] : 0.f;
    } else {                             // adjacency bitmask from edge_index
        int e = (b - 3328) * 256 + t;
        int s = a.ei[e];                 // src
        int d = a.ei[EE + e];            // dst
        atomicOr(&mask[d * 4 + (s >> 6)], 1ull << (s & 63));
    }
}

// Row-parallel GEMM: C[256 x NCOL] = A[256 x KDIM] @ B[KDIM x NCOL].
// 4 rows per block; A loads are wave-uniform (scalarized), B streamed coalesced.
template <int KDIM, int NCOL>
__global__ __launch_bounds__(256) void rowgemm(const float* __restrict__ A, long sA,
                                               const float* __restrict__ B, long sB,
                                               float* __restrict__ C, long sC) {
    A += (long)blockIdx.z * sA + (long)blockIdx.x * 4 * KDIM;
    B += (long)blockIdx.z * sB;
    C += (long)blockIdx.z * sC + (long)blockIdx.x * 4 * NCOL;
    int t = threadIdx.x;
    if (NCOL == 512) {
        const float2* B2 = (const float2*)B;
        float2 a0 = {0.f, 0.f}, a1 = {0.f, 0.f}, a2 = {0.f, 0.f}, a3 = {0.f, 0.f};
        #pragma unroll 4
        for (int k = 0; k < KDIM; k++) {
            float2 bv = B2[k * (NCOL / 2) + t];
            float w0 = A[0 * KDIM + k], w1 = A[1 * KDIM + k];
            float w2 = A[2 * KDIM + k], w3 = A[3 * KDIM + k];
            a0.x += w0 * bv.x; a0.y += w0 * bv.y;
            a1.x += w1 * bv.x; a1.y += w1 * bv.y;
            a2.x += w2 * bv.x; a2.y += w2 * bv.y;
            a3.x += w3 * bv.x; a3.y += w3 * bv.y;
        }
        float2* C2 = (float2*)C;
        C2[0 * (NCOL / 2) + t] = a0;
        C2[1 * (NCOL / 2) + t] = a1;
        C2[2 * (NCOL / 2) + t] = a2;
        C2[3 * (NCOL / 2) + t] = a3;
    } else {
        float a0 = 0.f, a1 = 0.f, a2 = 0.f, a3 = 0.f;
        #pragma unroll 4
        for (int k = 0; k < KDIM; k++) {
            float bv = B[k * NCOL + t];
            a0 += A[0 * KDIM + k] * bv;
            a1 += A[1 * KDIM + k] * bv;
            a2 += A[2 * KDIM + k] * bv;
            a3 += A[3 * KDIM + k] * bv;
        }
        C[0 * NCOL + t] = a0;
        C[1 * NCOL + t] = a1;
        C[2 * NCOL + t] = a2;
        C[3 * NCOL + t] = a3;
    }
}

// K[o][0:510] -> KdT[k][o] = K[o][k]-K[o][255+k], KbT[k][o] = K[o][255+k]; beff = K[:,510]
__global__ __launch_bounds__(256) void split_kernel(float* __restrict__ ws) {
    int l = blockIdx.y, k = blockIdx.x, o = threadIdx.x;
    const float* Kp = ws + OFF_K + l * 131072;
    if (k < 256) {
        float d = 0.f, bb = 0.f;
        if (k < FF) {
            float k1 = Kp[o * 512 + k];
            float k2 = Kp[o * 512 + FF + k];
            d = k1 - k2; bb = k2;
        }
        ws[OFF_KDT + l * 65536 + k * 256 + o] = d;
        ws[OFF_KBT + l * 65536 + k * 256 + o] = bb;
    } else {
        ws[OFF_BEFF + l * 256 + o] = Kp[o * 512 + F2];
    }
}

// Per-dst masked max over V rows + epilogue (bias, residual, relu).
__global__ __launch_bounds__(256) void agg_kernel(const float* __restrict__ U,
                                                  const float* __restrict__ V,
                                                  const float* __restrict__ beff,
                                                  const float* __restrict__ gprev,
                                                  float* __restrict__ gout,
                                                  float* __restrict__ g3c,
                                                  const unsigned long long* __restrict__ mask,
                                                  int has_res) {
    int i = blockIdx.x, f = threadIdx.x;
    __shared__ unsigned long long mw[4];
    if (f < 4) mw[f] = mask[i * 4 + f];
    __syncthreads();
    unsigned long long m0 = mw[0], m1 = mw[1], m2 = mw[2], m3 = mw[3];
    unsigned long long mr[4] = {m0, m1, m2, m3};
    float vm = -INFINITY;
    #pragma unroll
    for (int w = 0; w < 4; w++) {
        unsigned long long mword = mr[w];
        const float* Vp = V + w * 64 * 256 + f;
        #pragma unroll 8
        for (int j = 0; j < 64; j++) {
            float v = Vp[j * 256];
            vm = ((mword >> j) & 1) ? fmaxf(vm, v) : vm;
        }
    }
    bool any = (m0 | m1 | m2 | m3) != 0ull;
    float val = any ? (U[i * 256 + f] + beff[f] + vm) : 0.f;
    if (has_res) val += gprev[i * 256 + f];
    float g = fmaxf(val, 0.f);
    gout[i * 256 + f] = g;
    if (g3c && f < FF) g3c[i * FF + f] = g;
}

// y = relu(l4_W @ g3c + l4_b); 2 rows per block (1024 blocks -> 16 waves/CU),
// nontemporal W stream (read-once, 534 MB >> L3).
__global__ __launch_bounds__(256) void l4_kernel(const float* __restrict__ W,
                                                 const float* __restrict__ bias,
                                                 const float* __restrict__ g3c,
                                                 float* __restrict__ y) {
    int row0 = blockIdx.x * 2;
    int t = threadIdx.x;
    const vf4* W4 = (const vf4*)W;
    const vf4* G4 = (const vf4*)g3c;
    const int K4 = 65280 / 4;   // 16320
    float a0 = 0.f, a1 = 0.f;
    const vf4* w0p = W4 + (long)(row0 + 0) * K4;
    const vf4* w1p = W4 + (long)(row0 + 1) * K4;
    for (int v = t; v < K4; v += 256) {
        vf4 g  = G4[v];
        vf4 w0 = __builtin_nontemporal_load(&w0p[v]);
        vf4 w1 = __builtin_nontemporal_load(&w1p[v]);
        a0 += w0.x * g.x + w0.y * g.y + w0.z * g.z + w0.w * g.w;
        a1 += w1.x * g.x + w1.y * g.y + w1.z * g.z + w1.w * g.w;
    }
    #pragma unroll
    for (int off = 32; off; off >>= 1) {
        a0 += __shfl_xor(a0, off);
        a1 += __shfl_xor(a1, off);
    }
    __shared__ float red[4][2];
    int wv = t >> 6, ln = t & 63;
    if (ln == 0) { red[wv][0] = a0; red[wv][1] = a1; }
    __syncthreads();
    if (t < 2) {
        float s = red[0][t] + red[1][t] + red[2][t] + red[3][t];
        y[row0 + t] = fmaxf(s + bias[row0 + t], 0.f);
    }
}

// out = out_W @ y + out_b; one wave per row, nontemporal W stream.
__global__ __launch_bounds__(256) void out_kernel(const float* __restrict__ W,
                                                  const float* __restrict__ bias,
                                                  const float* __restrict__ y,
                                                  float* __restrict__ out) {
    int wv = threadIdx.x >> 6, ln = threadIdx.x & 63;
    int r = blockIdx.x * 4 + wv;
    const vf4* W4 = (const vf4*)(W + (long)r * HH);
    const vf4* Y4 = (const vf4*)y;
    float acc = 0.f;
    #pragma unroll
    for (int i = 0; i < 8; i++) {
        vf4 w  = __builtin_nontemporal_load(&W4[ln + 64 * i]);
        vf4 yy = Y4[ln + 64 * i];
        acc += w.x * yy.x + w.y * yy.y + w.z * yy.z + w.w * yy.w;
    }
    #pragma unroll
    for (int off = 32; off; off >>= 1) acc += __shfl_xor(acc, off);
    if (ln == 0) out[r] = acc + bias[r];
}

extern "C" void kernel_launch(void* const* d_in, const int* in_sizes, int n_in,
                              void* d_out, int out_size, void* d_ws, size_t ws_size,
                              hipStream_t stream) {
    float* ws = (float*)d_ws;
    unsigned long long* mask = (unsigned long long*)((char*)d_ws + OFF_MASK_BYTES);

    PrepArgs pa;
    pa.x  = (const float*)d_in[0];
    pa.ei = (const int*)d_in[1];
    for (int l = 0; l < 3; l++) {
        pa.W1[l] = (const float*)d_in[2 + l * 6 + 0];
        pa.b1[l] = (const float*)d_in[2 + l * 6 + 1];
        pa.W2[l] = (const float*)d_in[2 + l * 6 + 2];
        pa.b2[l] = (const float*)d_in[2 + l * 6 + 3];
        pa.W3[l] = (const float*)d_in[2 + l * 6 + 4];
        pa.b3[l] = (const float*)d_in[2 + l * 6 + 5];
    }
    const float* l4W  = (const float*)d_in[20];
    const float* l4b  = (const float*)d_in[21];
    const float* outW = (const float*)d_in[22];
    const float* outb = (const float*)d_in[23];

    (void)hipMemsetAsync(mask, 0, 8192, stream);
    prep_kernel<<<3584, 256, 0, stream>>>(pa, ws, mask);

    // T = W2p @ W1p  (per layer, batched over z)
    rowgemm<512, 512><<<dim3(64, 1, 3), 256, 0, stream>>>(
        ws + OFF_W2P, 131072, ws + OFF_W1P, 262144, ws + OFF_T, 131072);
    // K = W3p @ T
    rowgemm<256, 512><<<dim3(64, 1, 3), 256, 0, stream>>>(
        ws + OFF_W3P, 65536, ws + OFF_T, 131072, ws + OFF_K, 131072);
    split_kernel<<<dim3(257, 3), 256, 0, stream>>>(ws);

    for (int l = 0; l < 3; l++) {
        const float* gprev = ws + OFF_GP + l * 65536;
        float* gout = ws + OFF_GP + (l + 1) * 65536;
        // z=0: U = g @ KdT; z=1: V = g @ KbT   (KbT = KdT + 196608, V = U + 65536)
        rowgemm<256, 256><<<dim3(64, 1, 2), 256, 0, stream>>>(
            gprev, 0, ws + OFF_KDT + l * 65536, OFF_KBT - OFF_KDT, ws + OFF_U, 65536);
        agg_kernel<<<256, 256, 0, stream>>>(
            ws + OFF_U, ws + OFF_V, ws + OFF_BEFF + l * 256,
            gprev, gout, (l == 2) ? (ws + OFF_G3C) : nullptr, mask, (l > 0) ? 1 : 0);
    }

    l4_kernel<<<1024, 256, 0, stream>>>(l4W, l4b, ws + OFF_G3C, ws + OFF_Y);
    out_kernel<<<8160, 256, 0, stream>>>(outW, outb, ws + OFF_Y, (float*)d_out);
}